// Round 2
// baseline (171158.655 us; speedup 1.0000x reference)
//
#include <hip/hip_runtime.h>
#include <hip/hip_bf16.h>

#define NCLS 3
#define NPTS 64
#define NEDGE 2016   // 64*63/2
#define MIN_SAMP 200
#define SLOTS 32768  // write-once column slots per class (usage ~claims+displacements << SLOTS)

// Module-static device storage (no dependence on ws_size).
__device__ int          g_counts[NCLS];
__device__ int          g_sel[NCLS][NPTS];
__device__ float        g_Dm[NCLS][NPTS * NPTS];
__device__ float        g_tp[NCLS];
__device__ unsigned int g_store[NCLS][SLOTS][64];   // write-once published columns (25 MB)

__global__ void init_k() {
    if (threadIdx.x < NCLS) g_counts[threadIdx.x] = 0;
}

__global__ __launch_bounds__(256) void count_k(const int* __restrict__ labels, int N) {
    __shared__ int c3[NCLS];
    if (threadIdx.x < NCLS) c3[threadIdx.x] = 0;
    __syncthreads();
    for (int i = blockIdx.x * blockDim.x + threadIdx.x; i < N; i += gridDim.x * blockDim.x) {
        int c = labels[i];
        if ((unsigned)c < NCLS) atomicAdd(&c3[c], 1);
    }
    __syncthreads();
    if (threadIdx.x < NCLS) atomicAdd(&g_counts[threadIdx.x], c3[threadIdx.x]);
}

// One wave: first 64 indices per class in ascending order via ballot-scan.
__global__ __launch_bounds__(64) void select_k(const int* __restrict__ labels, int N) {
    const int lane = threadIdx.x;
    int cnt[NCLS] = {0, 0, 0};
    for (int base = 0; base < N; base += 64) {
        if (cnt[0] >= NPTS && cnt[1] >= NPTS && cnt[2] >= NPTS) break;
        int lab = (base + lane < N) ? labels[base + lane] : -1;
        for (int c = 0; c < NCLS; ++c) {
            if (cnt[c] >= NPTS) continue;
            unsigned long long m = __ballot(lab == c);
            if (!m) continue;
            int pos = cnt[c] + __popcll(m & ((1ull << lane) - 1ull));
            if (lab == c && pos < NPTS) g_sel[c][pos] = base + lane;
            cnt[c] = min(NPTS, cnt[c] + (int)__popcll(m));
        }
    }
}

__global__ __launch_bounds__(1024) void dist_k(const float* __restrict__ feat) {
    int cls = blockIdx.x;
    if (g_counts[cls] < MIN_SAMP) return;
    for (int p = threadIdx.x; p < NPTS * NPTS; p += 1024) {
        int i = p >> 6, j = p & 63;
        const float4* pi = (const float4*)(feat + (size_t)g_sel[cls][i] * 768);
        const float4* pj = (const float4*)(feat + (size_t)g_sel[cls][j] * 768);
        float sq = 0.f;
        #pragma unroll 4
        for (int d = 0; d < 192; ++d) {
            float4 va = pi[d], vb = pj[d];
            float dx = va.x - vb.x, dy = va.y - vb.y, dz = va.z - vb.z, dw = va.w - vb.w;
            sq = fmaf(dx, dx, sq); sq = fmaf(dy, dy, sq);
            sq = fmaf(dz, dz, sq); sq = fmaf(dw, dw, sq);
        }
        g_Dm[cls][p] = sqrtf(fmaxf(sq, 1e-12f));
    }
}

// lane-local word of the 2016-bit column bitset for bit index x
__device__ __forceinline__ unsigned int bitw(int x, int lane) {
    return ((x >> 5) == lane) ? (1u << (x & 31)) : 0u;
}

// atomicMin on LDS u64 via CAS; returns value seen before our (possible) write.
__device__ __forceinline__ unsigned long long lds_min_u64(unsigned long long* p, unsigned long long v) {
    unsigned long long cur = *((volatile unsigned long long*)p);
    while (v < cur) {
        unsigned long long prev = atomicCAS(p, cur, v);
        if (prev == cur) return cur;
        cur = prev;
    }
    return cur;
}

// One workgroup (16 waves) per class: lock-free parallel boundary-matrix reduction.
// Correctness: final pivot pairing of a boundary matrix is invariant under any
// sequence of "XOR an earlier-priority column into a later one"; columns are
// published to write-once slots, ownership by atomicMin(pri) — deterministic result.
__global__ __launch_bounds__(1024) void persist_k() {
    const int cls  = blockIdx.x;
    const int tid  = threadIdx.x;
    const int lane = tid & 63;
    const int wid  = tid >> 6;
    if (g_counts[cls] < MIN_SAMP) return;

    __shared__ float              sDm[NPTS * NPTS];      // 16 KB
    __shared__ short              rank2d[NPTS * NPTS];   // 8 KB
    __shared__ unsigned char      e2i[NEDGE], e2j[NEDGE];    // 4 KB
    __shared__ unsigned char      se_i[NEDGE], se_j[NEDGE];  // 4 KB
    __shared__ float              ev[NEDGE];             // 8 KB
    __shared__ unsigned long long owner[NEDGE];          // 16 KB  (pri<<32 | slot)
    __shared__ int                next_r, slotctr;
    __shared__ double             wacc[16];

    for (int p = tid; p < NPTS * NPTS; p += 1024) sDm[p] = g_Dm[cls][p];
    if (tid < NPTS - 1) {
        int i = tid;
        int base = i * (2 * NPTS - 1 - i) / 2;
        for (int j = i + 1; j < NPTS; ++j) {
            e2i[base + j - i - 1] = (unsigned char)i;
            e2j[base + j - i - 1] = (unsigned char)j;
        }
    }
    for (int p = tid; p < NEDGE; p += 1024) owner[p] = ~0ull;
    if (tid == 0) { next_r = 0; slotctr = 0; }
    __syncthreads();

    // Rank edges by (value, i, j) — matches reference lexsort((jj,ii,vals)).
    for (int e = tid; e < NEDGE; e += 1024) {
        int i_ = e2i[e], j_ = e2j[e];
        float v = sDm[i_ * NPTS + j_];
        int rk = 0;
        for (int f = 0; f < NEDGE; ++f) {
            int fi = e2i[f], fj = e2j[f];
            float w = sDm[fi * NPTS + fj];
            bool less = (w < v) || (w == v && (fi < i_ || (fi == i_ && fj < j_)));
            rk += less ? 1 : 0;
        }
        se_i[rk] = (unsigned char)i_;
        se_j[rk] = (unsigned char)j_;
        ev[rk]   = v;
        rank2d[i_ * NPTS + j_] = (short)rk;
        rank2d[j_ * NPTS + i_] = (short)rk;
    }
    __syncthreads();

    unsigned int* colstore = &g_store[cls][0][0];

    // Each wave grabs edge-rank groups dynamically; one triangle column at a time.
    while (true) {
        int r;
        if (lane == 0) r = atomicAdd(&next_r, 1);
        r = __shfl(r, 0);
        if (r >= NEDGE) break;
        const int i_ = se_i[r], j_ = se_j[r];
        short a_l = rank2d[i_ * NPTS + lane];
        short b_l = rank2d[j_ * NPTS + lane];
        bool valid = (lane != i_) && (lane != j_) && (a_l < r) && (b_l < r);
        unsigned long long mask = __ballot(valid);
        if (!mask) continue;
        const int kmin = __builtin_ctzll(mask);
        const int a0 = __shfl((int)a_l, kmin), b0 = __shfl((int)b_l, kmin);

        unsigned long long mm = mask;
        while (mm) {
            const int k = __builtin_ctzll(mm); mm &= mm - 1;
            const int a = __shfl((int)a_l, k), b = __shfl((int)b_l, k);
            unsigned long long mypack = ((unsigned long long)(r * 64 + k)) << 32;
            unsigned int colw;
            if (k == kmin) {
                // group-leader column: {a,b,r}, claims pivot r (apparent pair, 0 persistence)
                colw = bitw(a, lane) ^ bitw(b, lane) ^ bitw(r, lane);
            } else {
                // pre-reduced by leader: {a,b} ^ {a0,b0}
                colw = bitw(a, lane) ^ bitw(b, lane) ^ bitw(a0, lane) ^ bitw(b0, lane);
            }
            // lock-free reduction of this column
            while (true) {
                unsigned long long m2 = __ballot(colw != 0u);
                if (!m2) break;                               // positive column
                int hl = 63 - __builtin_clzll(m2);
                unsigned int hw = (unsigned int)__shfl((int)colw, hl);
                int piv = (hl << 5) | (31 - __builtin_clz(hw));
                unsigned long long cur = ((volatile unsigned long long*)owner)[piv];
                if (cur < mypack) {                           // earlier column owns it: XOR it in
                    __threadfence();
                    colw ^= colstore[(size_t)(unsigned)(cur & 0xffffffffu) * 64 + lane];
                    continue;
                }
                // claim attempt: publish to a fresh write-once slot, then atomicMin
                int slot;
                if (lane == 0) slot = atomicAdd(&slotctr, 1);
                slot = __shfl(slot, 0) & (SLOTS - 1);
                colstore[(size_t)slot * 64 + lane] = colw;
                __threadfence();
                unsigned long long mp = mypack | (unsigned)slot;
                unsigned long long old;
                if (lane == 0) old = lds_min_u64(&owner[piv], mp);
                old = __shfl(old, 0);
                if (old == ~0ull) break;                      // claimed fresh pivot: done
                __threadfence();
                if (old < mp) {                               // lost a race: XOR winner, go on
                    colw ^= colstore[(size_t)(unsigned)(old & 0xffffffffu) * 64 + lane];
                    continue;
                }
                // displaced a later column: adopt it and keep reducing
                colw = colstore[(size_t)(unsigned)(old & 0xffffffffu) * 64 + lane];
                mypack = old & 0xffffffff00000000ull;
            }
        }
    }
    __syncthreads();

    // Sweep final ownership: pers = sum over claimed pivots of tval[pri] - ev[piv]
    double local = 0.0;
    for (int piv = tid; piv < NEDGE; piv += 1024) {
        unsigned long long o = owner[piv];
        if (o != ~0ull) {
            int pri = (int)(o >> 32);
            local += (double)ev[pri >> 6] - (double)ev[piv];
        }
    }
    for (int off = 32; off; off >>= 1) local += __shfl_down(local, off);
    if (lane == 0) wacc[wid] = local;
    __syncthreads();
    if (tid == 0) {
        double s = 0.0;
        for (int w = 0; w < 16; ++w) s += wacc[w];
        g_tp[cls] = (float)s;
    }
}

__global__ void final_k(const float* __restrict__ tgt, float* __restrict__ out) {
    double total = 0.0;
    int valid = 0;
    for (int c = 0; c < NCLS; ++c) {
        if (g_counts[c] >= MIN_SAMP) {
            double tpt = 0.0;
            for (int p = 0; p < 100; ++p)
                tpt += (double)tgt[(c * 100 + p) * 2 + 1] - (double)tgt[(c * 100 + p) * 2 + 0];
            double d = (double)g_tp[c] - tpt;
            total += d * d;
            valid++;
        }
    }
    *out = valid ? (float)(total / valid) : 0.0f;
}

extern "C" void kernel_launch(void* const* d_in, const int* in_sizes, int n_in,
                              void* d_out, int out_size, void* d_ws, size_t ws_size,
                              hipStream_t stream) {
    const float* feat   = (const float*)d_in[0];
    const int*   labels = (const int*)d_in[1];
    const float* tgt    = (const float*)d_in[2];
    const int N = in_sizes[1];

    hipLaunchKernelGGL(init_k,   dim3(1),    dim3(64),   0, stream);
    hipLaunchKernelGGL(count_k,  dim3(256),  dim3(256),  0, stream, labels, N);
    hipLaunchKernelGGL(select_k, dim3(1),    dim3(64),   0, stream, labels, N);
    hipLaunchKernelGGL(dist_k,   dim3(NCLS), dim3(1024), 0, stream, feat);
    hipLaunchKernelGGL(persist_k,dim3(NCLS), dim3(1024), 0, stream);
    hipLaunchKernelGGL(final_k,  dim3(1),    dim3(1),    0, stream, tgt, (float*)d_out);
}

// Round 3
// 18520.331 us; speedup vs baseline: 9.2417x; 9.2417x over previous
//
#include <hip/hip_runtime.h>
#include <hip/hip_bf16.h>

#define NCLS 3
#define NPTS 64
#define NEDGE 2016   // 64*63/2
#define MIN_SAMP 200

// Module-static device storage (no dependence on ws_size).
__device__ int          g_counts[NCLS];
__device__ int          g_sel[NCLS][NPTS];
__device__ float        g_Dm[NCLS][NPTS * NPTS];
__device__ float        g_tp[NCLS];
__device__ unsigned int g_rows[NCLS][NEDGE][64];   // null-space row-bitmask matrix, 516KB/class

__global__ void init_k() {
    if (threadIdx.x < NCLS) g_counts[threadIdx.x] = 0;
}

__global__ __launch_bounds__(256) void count_k(const int* __restrict__ labels, int N) {
    __shared__ int c3[NCLS];
    if (threadIdx.x < NCLS) c3[threadIdx.x] = 0;
    __syncthreads();
    for (int i = blockIdx.x * blockDim.x + threadIdx.x; i < N; i += gridDim.x * blockDim.x) {
        int c = labels[i];
        if ((unsigned)c < NCLS) atomicAdd(&c3[c], 1);
    }
    __syncthreads();
    if (threadIdx.x < NCLS) atomicAdd(&g_counts[threadIdx.x], c3[threadIdx.x]);
}

// One wave: first 64 indices per class in ascending order via ballot-scan.
__global__ __launch_bounds__(64) void select_k(const int* __restrict__ labels, int N) {
    const int lane = threadIdx.x;
    int cnt[NCLS] = {0, 0, 0};
    for (int base = 0; base < N; base += 64) {
        if (cnt[0] >= NPTS && cnt[1] >= NPTS && cnt[2] >= NPTS) break;
        int lab = (base + lane < N) ? labels[base + lane] : -1;
        for (int c = 0; c < NCLS; ++c) {
            if (cnt[c] >= NPTS) continue;
            unsigned long long m = __ballot(lab == c);
            if (!m) continue;
            int pos = cnt[c] + __popcll(m & ((1ull << lane) - 1ull));
            if (lab == c && pos < NPTS) g_sel[c][pos] = base + lane;
            cnt[c] = min(NPTS, cnt[c] + (int)__popcll(m));
        }
    }
}

__global__ __launch_bounds__(1024) void dist_k(const float* __restrict__ feat) {
    int cls = blockIdx.x;
    if (g_counts[cls] < MIN_SAMP) return;
    for (int p = threadIdx.x; p < NPTS * NPTS; p += 1024) {
        int i = p >> 6, j = p & 63;
        const float4* pi = (const float4*)(feat + (size_t)g_sel[cls][i] * 768);
        const float4* pj = (const float4*)(feat + (size_t)g_sel[cls][j] * 768);
        float sq = 0.f;
        #pragma unroll 4
        for (int d = 0; d < 192; ++d) {
            float4 va = pi[d], vb = pj[d];
            float dx = va.x - vb.x, dy = va.y - vb.y, dz = va.z - vb.z, dw = va.w - vb.w;
            sq = fmaf(dx, dx, sq); sq = fmaf(dy, dy, sq);
            sq = fmaf(dz, dz, sq); sq = fmaf(dw, dw, sq);
        }
        g_Dm[cls][p] = sqrtf(fmaxf(sq, 1e-12f));
    }
}

// One workgroup per class. tp = sum(deaths) - sum(births).
// births: positive (non-forest) edges via union-find (Kruskal in rank order).
// deaths: greedy GF(2) basis of triangle boundary columns {a,b,r}; membership
// tested against the maintained null-space complement (Row matrix) -> no
// column fill-in, no reduction chains. Matroid => value-sum invariant to
// tie-order and pivot rule; matches the reference reduction exactly.
__global__ __launch_bounds__(1024) void persist_k() {
    const int cls  = blockIdx.x;
    const int tid  = threadIdx.x;
    const int lane = tid & 63;
    const int wid  = tid >> 6;
    if (g_counts[cls] < MIN_SAMP) return;

    union PhaseU {
        float        sDm[NPTS * NPTS];   // phase 1: distances
        unsigned int pbuf[62][64];       // phase 2: candidate p-vectors
    };
    __shared__ PhaseU        u;                       // 16 KB
    __shared__ short         rank2d[NPTS * NPTS];     // 8 KB
    __shared__ unsigned char e2i[NEDGE], e2j[NEDGE];  // 4 KB
    __shared__ unsigned char se_i[NEDGE], se_j[NEDGE];// 4 KB
    __shared__ float         ev[NEDGE];               // 8 KB
    __shared__ unsigned char cstate[64];
    __shared__ int           s_t;
    __shared__ double        s_birth, s_death;
    __shared__ unsigned char parent[NPTS];

    for (int p = tid; p < NPTS * NPTS; p += 1024) u.sDm[p] = g_Dm[cls][p];
    if (tid < NPTS - 1) {
        int i = tid;
        int base = i * (2 * NPTS - 1 - i) / 2;
        for (int j = i + 1; j < NPTS; ++j) {
            e2i[base + j - i - 1] = (unsigned char)i;
            e2j[base + j - i - 1] = (unsigned char)j;
        }
    }
    // identity-initialize the Row matrix (global, L2-resident)
    for (int x = tid; x < NEDGE * 64; x += 1024) {
        int rr = x >> 6, w = x & 63;
        g_rows[cls][rr][w] = (w == (rr >> 5)) ? (1u << (rr & 31)) : 0u;
    }
    __syncthreads();

    // Rank edges by (value, i, j) — matches reference lexsort((jj,ii,vals)).
    for (int e = tid; e < NEDGE; e += 1024) {
        int i_ = e2i[e], j_ = e2j[e];
        float v = u.sDm[i_ * NPTS + j_];
        int rk = 0;
        for (int f = 0; f < NEDGE; ++f) {
            int fi = e2i[f], fj = e2j[f];
            float w = u.sDm[fi * NPTS + fj];
            bool less = (w < v) || (w == v && (fi < i_ || (fi == i_ && fj < j_)));
            rk += less ? 1 : 0;
        }
        se_i[rk] = (unsigned char)i_;
        se_j[rk] = (unsigned char)j_;
        ev[rk]   = v;
        rank2d[i_ * NPTS + j_] = (short)rk;
        rank2d[j_ * NPTS + i_] = (short)rk;
    }
    __syncthreads();

    // Kruskal union-find: sum of birth (positive-edge) values.
    if (tid == 0) {
        for (int i = 0; i < NPTS; ++i) parent[i] = (unsigned char)i;
        double bs = 0.0;
        for (int r = 0; r < NEDGE; ++r) {
            int x = se_i[r]; while (parent[x] != x) { parent[x] = parent[parent[x]]; x = parent[x]; }
            int y = se_j[r]; while (parent[y] != y) { parent[y] = parent[parent[y]]; y = parent[y]; }
            if (x == y) bs += (double)ev[r];
            else parent[x] = (unsigned char)y;
        }
        s_birth = bs; s_death = 0.0;
    }
    __syncthreads();   // sDm dead from here; u.pbuf live

    unsigned int (*Row)[64] = g_rows[cls];

    for (int r = 1; r < NEDGE; ++r) {
        const int i_ = se_i[r], j_ = se_j[r];
        const int a_l = rank2d[i_ * NPTS + lane];
        const int b_l = rank2d[j_ * NPTS + lane];
        const bool valid = (lane != i_) && (lane != j_) && (a_l < r) && (b_l < r);
        const unsigned long long mask = __ballot(valid);
        if (!mask) continue;               // uniform across waves: no barrier needed
        const int cnt = __popcll(mask);

        // Test phase: wave w tests candidates idx = w, w+16, ... (read-only on Row)
        {
            const unsigned int rrow = Row[r][lane];
            for (int idx = wid; idx < cnt; idx += 16) {
                unsigned long long mm = mask;
                for (int s = 0; s < idx; ++s) mm &= mm - 1;
                const int k = __builtin_ctzll(mm);
                const int a = __shfl(a_l, k);
                const int b = __shfl(b_l, k);
                const unsigned int p = Row[a][lane] ^ Row[b][lane] ^ rrow;
                u.pbuf[idx][lane] = p;
                const bool indep = (__ballot(p != 0u) != 0ull);
                if (lane == 0) cstate[idx] = indep ? 1 : 0;
            }
        }
        __syncthreads();

        // Resolution: accept claimants in order; rank-1 update; retest survivors.
        while (true) {
            int c = -1;
            for (int x = 0; x < cnt; ++x) if (cstate[x] == 1) { c = x; break; }
            if (c < 0) break;              // uniform (cstate stable since last barrier)
            __syncthreads();               // everyone done scanning before mutation
            if (wid == 0) {
                const unsigned int pw = u.pbuf[c][lane];
                const unsigned long long m2 = __ballot(pw != 0u);
                const int fl = __builtin_ctzll(m2);
                const unsigned int w0 = (unsigned int)__shfl((int)pw, fl);
                if (lane == 0) s_t = fl * 32 + __builtin_ctz(w0);
            }
            if (tid == 0) { s_death += (double)ev[r]; cstate[c] = 2; }
            __syncthreads();
            const int t = s_t, tw = t >> 5;
            const unsigned int tb = 1u << (t & 31);
            const unsigned int pw = u.pbuf[c][lane];
            // rank-1 update: Row[rr] ^= p for every row rr holding bit t
            for (int rr0 = wid * 64; rr0 < NEDGE; rr0 += 1024) {
                const int rr = rr0 + lane;
                unsigned int hit = (rr < NEDGE) ? (Row[rr][tw] & tb) : 0u;
                unsigned long long mrows = __ballot(hit != 0u);
                while (mrows) {
                    const int rx = rr0 + __builtin_ctzll(mrows);
                    mrows &= mrows - 1;
                    Row[rx][lane] ^= pw;
                }
            }
            __threadfence_block();
            __syncthreads();
            // retest remaining claimants against the enlarged span
            {
                const unsigned int rrow2 = Row[r][lane];
                for (int idx = wid; idx < cnt; idx += 16) {
                    if (cstate[idx] != 1) continue;
                    unsigned long long mm = mask;
                    for (int s = 0; s < idx; ++s) mm &= mm - 1;
                    const int k = __builtin_ctzll(mm);
                    const int a = __shfl(a_l, k);
                    const int b = __shfl(b_l, k);
                    const unsigned int p2 = Row[a][lane] ^ Row[b][lane] ^ rrow2;
                    u.pbuf[idx][lane] = p2;
                    const bool indep = (__ballot(p2 != 0u) != 0ull);
                    if (lane == 0) cstate[idx] = indep ? 1 : 0;
                }
            }
            __syncthreads();
        }
        __syncthreads();                   // protect cstate/pbuf before next group
    }

    if (tid == 0) g_tp[cls] = (float)(s_death - s_birth);
}

__global__ void final_k(const float* __restrict__ tgt, float* __restrict__ out) {
    double total = 0.0;
    int valid = 0;
    for (int c = 0; c < NCLS; ++c) {
        if (g_counts[c] >= MIN_SAMP) {
            double tpt = 0.0;
            for (int p = 0; p < 100; ++p)
                tpt += (double)tgt[(c * 100 + p) * 2 + 1] - (double)tgt[(c * 100 + p) * 2 + 0];
            double d = (double)g_tp[c] - tpt;
            total += d * d;
            valid++;
        }
    }
    *out = valid ? (float)(total / valid) : 0.0f;
}

extern "C" void kernel_launch(void* const* d_in, const int* in_sizes, int n_in,
                              void* d_out, int out_size, void* d_ws, size_t ws_size,
                              hipStream_t stream) {
    const float* feat   = (const float*)d_in[0];
    const int*   labels = (const int*)d_in[1];
    const float* tgt    = (const float*)d_in[2];
    const int N = in_sizes[1];

    hipLaunchKernelGGL(init_k,   dim3(1),    dim3(64),   0, stream);
    hipLaunchKernelGGL(count_k,  dim3(256),  dim3(256),  0, stream, labels, N);
    hipLaunchKernelGGL(select_k, dim3(1),    dim3(64),   0, stream, labels, N);
    hipLaunchKernelGGL(dist_k,   dim3(NCLS), dim3(1024), 0, stream, feat);
    hipLaunchKernelGGL(persist_k,dim3(NCLS), dim3(1024), 0, stream);
    hipLaunchKernelGGL(final_k,  dim3(1),    dim3(1),    0, stream, tgt, (float*)d_out);
}

// Round 5
// 7077.970 us; speedup vs baseline: 24.1819x; 2.6166x over previous
//
#include <hip/hip_runtime.h>
#include <hip/hip_bf16.h>

#define NCLS 3
#define NPTS 64
#define NEDGE 2016   // 64*63/2
#define MIN_SAMP 200
#define CW 4         // annotation capacity = 128 class slots (4 u32)

__device__ int          g_counts[NCLS];
__device__ int          g_sel[NCLS][NPTS];
__device__ float        g_Dm[NCLS][NPTS * NPTS];
__device__ float        g_tp[NCLS];
__device__ int          g_ovf[NCLS];
__device__ unsigned int g_rows[NCLS][NEDGE][64];   // fallback-only state

__global__ void init_k() {
    if (threadIdx.x < NCLS) { g_counts[threadIdx.x] = 0; g_ovf[threadIdx.x] = 0; }
}

__global__ __launch_bounds__(256) void count_k(const int* __restrict__ labels, int N) {
    __shared__ int c3[NCLS];
    if (threadIdx.x < NCLS) c3[threadIdx.x] = 0;
    __syncthreads();
    for (int i = blockIdx.x * blockDim.x + threadIdx.x; i < N; i += gridDim.x * blockDim.x) {
        int c = labels[i];
        if ((unsigned)c < NCLS) atomicAdd(&c3[c], 1);
    }
    __syncthreads();
    if (threadIdx.x < NCLS) atomicAdd(&g_counts[threadIdx.x], c3[threadIdx.x]);
}

__global__ __launch_bounds__(64) void select_k(const int* __restrict__ labels, int N) {
    const int lane = threadIdx.x;
    int cnt[NCLS] = {0, 0, 0};
    for (int base = 0; base < N; base += 64) {
        if (cnt[0] >= NPTS && cnt[1] >= NPTS && cnt[2] >= NPTS) break;
        int lab = (base + lane < N) ? labels[base + lane] : -1;
        for (int c = 0; c < NCLS; ++c) {
            if (cnt[c] >= NPTS) continue;
            unsigned long long m = __ballot(lab == c);
            if (!m) continue;
            int pos = cnt[c] + __popcll(m & ((1ull << lane) - 1ull));
            if (lab == c && pos < NPTS) g_sel[c][pos] = base + lane;
            cnt[c] = min(NPTS, cnt[c] + (int)__popcll(m));
        }
    }
}

__global__ __launch_bounds__(1024) void dist_k(const float* __restrict__ feat) {
    int cls = blockIdx.x;
    if (g_counts[cls] < MIN_SAMP) return;
    for (int p = threadIdx.x; p < NPTS * NPTS; p += 1024) {
        int i = p >> 6, j = p & 63;
        const float4* pi = (const float4*)(feat + (size_t)g_sel[cls][i] * 768);
        const float4* pj = (const float4*)(feat + (size_t)g_sel[cls][j] * 768);
        float sq = 0.f;
        #pragma unroll 4
        for (int d = 0; d < 192; ++d) {
            float4 va = pi[d], vb = pj[d];
            float dx = va.x - vb.x, dy = va.y - vb.y, dz = va.z - vb.z, dw = va.w - vb.w;
            sq = fmaf(dx, dx, sq); sq = fmaf(dy, dy, sq);
            sq = fmaf(dz, dz, sq); sq = fmaf(dw, dw, sq);
        }
        g_Dm[cls][p] = sqrtf(fmaxf(sq, 1e-12f));
    }
}

// ---------------- fast path: annotation-based exact H1 persistence ----------------
__global__ __launch_bounds__(1024) void persist_fast_k() {
    const int cls  = blockIdx.x;
    const int tid  = threadIdx.x;
    const int lane = tid & 63;
    const int wid  = tid >> 6;
    if (g_counts[cls] < MIN_SAMP) return;

    __shared__ union UA {
        float        sDm[NPTS * NPTS];          // ranking phase (16 KB)
        unsigned int M[NEDGE + NPTS][CW];       // annotations: edges + vertex potentials (33 KB)
    } uA;
    __shared__ short         rank2d[NPTS * NPTS];       // 8 KB
    __shared__ unsigned char se_i[NEDGE], se_j[NEDGE];  // 4 KB
    __shared__ float         ev[NEDGE];                 // 8 KB
    __shared__ union UB {
        struct { unsigned char e2i[NEDGE], e2j[NEDGE]; } rk;          // ranking
        struct { unsigned int vbuf[62][CW]; unsigned char cflag[62]; } t; // main loop
    } uB;
    __shared__ unsigned int  upd[62][CW];
    __shared__ int           updm[62];
    __shared__ unsigned char parent[NPTS];
    __shared__ unsigned int  occ[CW];
    __shared__ int           s_d, s_bail;

    for (int p = tid; p < NPTS * NPTS; p += 1024) uA.sDm[p] = g_Dm[cls][p];
    if (tid < NPTS - 1) {
        int i = tid;
        int base = i * (2 * NPTS - 1 - i) / 2;
        for (int j = i + 1; j < NPTS; ++j) {
            uB.rk.e2i[base + j - i - 1] = (unsigned char)i;
            uB.rk.e2j[base + j - i - 1] = (unsigned char)j;
        }
    }
    if (tid < NPTS) rank2d[tid * NPTS + tid] = 0x7fff;
    if (tid < NPTS) parent[tid] = (unsigned char)tid;
    if (tid < CW)   occ[tid] = 0u;
    if (tid == 0)   { s_bail = 0; s_d = 0; }
    __syncthreads();

    // Rank edges by (value, i, j) — matches reference lexsort((jj,ii,vals)).
    for (int e = tid; e < NEDGE; e += 1024) {
        int i_ = uB.rk.e2i[e], j_ = uB.rk.e2j[e];
        float v = uA.sDm[i_ * NPTS + j_];
        int rk = 0;
        for (int f = 0; f < NEDGE; ++f) {
            int fi = uB.rk.e2i[f], fj = uB.rk.e2j[f];
            float w = uA.sDm[fi * NPTS + fj];
            bool less = (w < v) || (w == v && (fi < i_ || (fi == i_ && fj < j_)));
            rk += less ? 1 : 0;
        }
        se_i[rk] = (unsigned char)i_;
        se_j[rk] = (unsigned char)j_;
        ev[rk]   = v;
        rank2d[i_ * NPTS + j_] = (short)rk;
        rank2d[j_ * NPTS + i_] = (short)rk;
    }
    __syncthreads();           // ranking done; sDm & e2i/e2j dead

    for (int x = tid; x < (NEDGE + NPTS) * CW; x += 1024)
        uA.M[x >> 2][x & 3] = 0u;
    __syncthreads();

    double birth = 0.0, death = 0.0;   // wave-0 registers

    for (int r = 0; r < NEDGE; ++r) {
        const int i_ = se_i[r], j_ = se_j[r];
        const int a_l = rank2d[i_ * NPTS + lane];
        const int b_l = rank2d[j_ * NPTS + lane];
        const bool validk = (lane != i_) && (lane != j_) && (a_l < r) && (b_l < r);
        const unsigned long long mask = __ballot(validk);
        const int c = __popcll(mask);

        // ---- edge event (wave 0, lane 0): DSU + annotation of edge r ----
        if (wid == 0 && lane == 0 && !s_bail) {
            int x = i_; while (parent[x] != x) { parent[x] = parent[parent[x]]; x = parent[x]; }
            int y = j_; while (parent[y] != y) { parent[y] = parent[parent[y]]; y = parent[y]; }
            unsigned int ann[CW];
            #pragma unroll
            for (int w = 0; w < CW; ++w) ann[w] = uA.M[NEDGE + i_][w] ^ uA.M[NEDGE + j_][w];
            if (x != y) {
                parent[x] = (unsigned char)y;            // negative edge: tree merge
            } else {
                birth += (double)ev[r];                  // positive edge: new H1 class
                int s = -1;
                #pragma unroll
                for (int w = 0; w < CW; ++w) {
                    if (s < 0) { unsigned int f = ~occ[w]; if (f) { s = w * 32 + __builtin_ctz(f); occ[w] |= 1u << (s & 31); } }
                }
                if (s < 0) { s_bail = 1; g_ovf[cls] = 1; }
                else ann[s >> 5] ^= 1u << (s & 31);
            }
            #pragma unroll
            for (int w = 0; w < CW; ++w) uA.M[r][w] = ann[w];
        }

        if (c == 0) continue;

        __syncthreads();                                  // B1: M[r] + prior updates visible
        if (s_bail) break;

        // ---- tests: candidate idx handled by wave (idx mod 16) ----
        for (int idx = wid; idx < c; idx += 16) {
            unsigned long long mm = mask;
            for (int s2 = 0; s2 < idx; ++s2) mm &= mm - 1;
            const int k = __builtin_ctzll(mm);
            const int a = __shfl(a_l, k);
            const int b = __shfl(b_l, k);
            unsigned int vw = 0;
            if (lane < CW) vw = uA.M[a][lane] ^ uA.M[b][lane] ^ uA.M[r][lane];
            const bool nz = (__ballot(vw != 0u) != 0ull);
            if (lane < CW) uB.t.vbuf[idx][lane] = vw;
            if (lane == 0) uB.t.cflag[idx] = nz ? 1 : 0;
        }
        __syncthreads();                                  // B2: vbuf/cflag visible

        // ---- batch Gauss-Jordan over candidates (wave 0; lane = candidate) ----
        if (wid == 0) {
            unsigned int v0 = 0, v1 = 0, v2 = 0, v3 = 0;
            if (lane < c && uB.t.cflag[lane]) {
                v0 = uB.t.vbuf[lane][0]; v1 = uB.t.vbuf[lane][1];
                v2 = uB.t.vbuf[lane][2]; v3 = uB.t.vbuf[lane][3];
            }
            unsigned int s0 = 0, s1 = 0, s2v = 0, s3 = 0;
            int accidx = -1, accm = 0;
            int d = 0;
            while (true) {
                unsigned long long nzm = __ballot((v0 | v1 | v2 | v3) != 0u);
                if (!nzm) break;
                const int l = __builtin_ctzll(nzm);
                const unsigned int p0 = (unsigned)__shfl((int)v0, l);
                const unsigned int p1 = (unsigned)__shfl((int)v1, l);
                const unsigned int p2 = (unsigned)__shfl((int)v2, l);
                const unsigned int p3 = (unsigned)__shfl((int)v3, l);
                const int m = p0 ? __builtin_ctz(p0) : p1 ? 32 + __builtin_ctz(p1)
                           : p2 ? 64 + __builtin_ctz(p2) : 96 + __builtin_ctz(p3);
                if (lane == l) { s0 = v0; s1 = v1; s2v = v2; s3 = v3; accidx = d; accm = m; }
                const int mw = m >> 5;
                const unsigned int mb = 1u << (m & 31);
                const unsigned int hv = (mw == 0 ? v0 : mw == 1 ? v1 : mw == 2 ? v2 : v3) & mb;
                if (hv) { v0 ^= p0; v1 ^= p1; v2 ^= p2; v3 ^= p3; }
                if (accidx >= 0 && accidx < d) {
                    const unsigned int hs = (mw == 0 ? s0 : mw == 1 ? s1 : mw == 2 ? s2v : s3) & mb;
                    if (hs) { s0 ^= p0; s1 ^= p1; s2v ^= p2; s3 ^= p3; }
                }
                ++d;
            }
            if (accidx >= 0) {
                upd[accidx][0] = s0; upd[accidx][1] = s1;
                upd[accidx][2] = s2v; upd[accidx][3] = s3;
                updm[accidx] = accm;
                atomicAnd(&occ[accm >> 5], ~(1u << (accm & 31)));   // free slot
            }
            if (lane == 0) { s_d = d; death += (double)d * (double)ev[r]; }
        }
        __syncthreads();                                  // B3: upd/updm/s_d visible

        const int d = s_d;
        if (d > 0) {
            if (wid == 0) {
                // wave 0 owns the 64 vertex-potential rows (consistency before next edge event)
                unsigned int* row = uA.M[NEDGE + lane];
                unsigned int r0 = row[0], r1 = row[1], r2 = row[2], r3 = row[3];
                bool ch = false;
                for (int t2 = 0; t2 < d; ++t2) {
                    const int m = updm[t2];
                    const unsigned int mb = 1u << (m & 31);
                    const unsigned int hw = (m < 32 ? r0 : m < 64 ? r1 : m < 96 ? r2 : r3);
                    if (hw & mb) { r0 ^= upd[t2][0]; r1 ^= upd[t2][1]; r2 ^= upd[t2][2]; r3 ^= upd[t2][3]; ch = true; }
                }
                if (ch) { row[0] = r0; row[1] = r1; row[2] = r2; row[3] = r3; }
            } else {
                for (int rr = tid - 64; rr < NEDGE; rr += 960) {
                    unsigned int* row = uA.M[rr];
                    unsigned int r0 = row[0], r1 = row[1], r2 = row[2], r3 = row[3];
                    bool ch = false;
                    for (int t2 = 0; t2 < d; ++t2) {
                        const int m = updm[t2];
                        const unsigned int mb = 1u << (m & 31);
                        const unsigned int hw = (m < 32 ? r0 : m < 64 ? r1 : m < 96 ? r2 : r3);
                        if (hw & mb) { r0 ^= upd[t2][0]; r1 ^= upd[t2][1]; r2 ^= upd[t2][2]; r3 ^= upd[t2][3]; ch = true; }
                    }
                    if (ch) { row[0] = r0; row[1] = r1; row[2] = r2; row[3] = r3; }
                }
            }
            // no trailing barrier: disjoint rows; B1 of the next candidate-edge orders reads
        }
    }

    if (wid == 0 && lane == 0 && !s_bail) g_tp[cls] = (float)(death - birth);
}

// ---------------- fallback: R3's validated exact Row-matrix reduction ----------------
__global__ __launch_bounds__(1024) void persist_exact_k() {
    const int cls  = blockIdx.x;
    const int tid  = threadIdx.x;
    const int lane = tid & 63;
    const int wid  = tid >> 6;
    if (g_counts[cls] < MIN_SAMP) return;
    if (!g_ovf[cls]) return;

    union PhaseU {
        float        sDm[NPTS * NPTS];
        unsigned int pbuf[62][64];
    };
    __shared__ PhaseU        u;
    __shared__ short         rank2d[NPTS * NPTS];
    __shared__ unsigned char e2i[NEDGE], e2j[NEDGE];
    __shared__ unsigned char se_i[NEDGE], se_j[NEDGE];
    __shared__ float         ev[NEDGE];
    __shared__ unsigned char cstate[64];
    __shared__ int           s_t;
    __shared__ double        s_birth, s_death;
    __shared__ unsigned char parent[NPTS];

    for (int p = tid; p < NPTS * NPTS; p += 1024) u.sDm[p] = g_Dm[cls][p];
    if (tid < NPTS - 1) {
        int i = tid;
        int base = i * (2 * NPTS - 1 - i) / 2;
        for (int j = i + 1; j < NPTS; ++j) {
            e2i[base + j - i - 1] = (unsigned char)i;
            e2j[base + j - i - 1] = (unsigned char)j;
        }
    }
    for (int x = tid; x < NEDGE * 64; x += 1024) {
        int rr = x >> 6, w = x & 63;
        g_rows[cls][rr][w] = (w == (rr >> 5)) ? (1u << (rr & 31)) : 0u;
    }
    if (tid < NPTS) rank2d[tid * NPTS + tid] = 0x7fff;
    __syncthreads();

    for (int e = tid; e < NEDGE; e += 1024) {
        int i_ = e2i[e], j_ = e2j[e];
        float v = u.sDm[i_ * NPTS + j_];
        int rk = 0;
        for (int f = 0; f < NEDGE; ++f) {
            int fi = e2i[f], fj = e2j[f];
            float w = u.sDm[fi * NPTS + fj];
            bool less = (w < v) || (w == v && (fi < i_ || (fi == i_ && fj < j_)));
            rk += less ? 1 : 0;
        }
        se_i[rk] = (unsigned char)i_;
        se_j[rk] = (unsigned char)j_;
        ev[rk]   = v;
        rank2d[i_ * NPTS + j_] = (short)rk;
        rank2d[j_ * NPTS + i_] = (short)rk;
    }
    __syncthreads();

    if (tid == 0) {
        for (int i = 0; i < NPTS; ++i) parent[i] = (unsigned char)i;
        double bs = 0.0;
        for (int r = 0; r < NEDGE; ++r) {
            int x = se_i[r]; while (parent[x] != x) { parent[x] = parent[parent[x]]; x = parent[x]; }
            int y = se_j[r]; while (parent[y] != y) { parent[y] = parent[parent[y]]; y = parent[y]; }
            if (x == y) bs += (double)ev[r];
            else parent[x] = (unsigned char)y;
        }
        s_birth = bs; s_death = 0.0;
    }
    __syncthreads();

    unsigned int (*Row)[64] = g_rows[cls];

    for (int r = 1; r < NEDGE; ++r) {
        const int i_ = se_i[r], j_ = se_j[r];
        const int a_l = rank2d[i_ * NPTS + lane];
        const int b_l = rank2d[j_ * NPTS + lane];
        const bool valid = (lane != i_) && (lane != j_) && (a_l < r) && (b_l < r);
        const unsigned long long mask = __ballot(valid);
        if (!mask) continue;
        const int cnt = __popcll(mask);

        {
            const unsigned int rrow = Row[r][lane];
            for (int idx = wid; idx < cnt; idx += 16) {
                unsigned long long mm = mask;
                for (int s = 0; s < idx; ++s) mm &= mm - 1;
                const int k = __builtin_ctzll(mm);
                const int a = __shfl(a_l, k);
                const int b = __shfl(b_l, k);
                const unsigned int p = Row[a][lane] ^ Row[b][lane] ^ rrow;
                u.pbuf[idx][lane] = p;
                const bool indep = (__ballot(p != 0u) != 0ull);
                if (lane == 0) cstate[idx] = indep ? 1 : 0;
            }
        }
        __syncthreads();

        while (true) {
            int c = -1;
            for (int x = 0; x < cnt; ++x) if (cstate[x] == 1) { c = x; break; }
            if (c < 0) break;
            __syncthreads();
            if (wid == 0) {
                const unsigned int pw = u.pbuf[c][lane];
                const unsigned long long m2 = __ballot(pw != 0u);
                const int fl = __builtin_ctzll(m2);
                const unsigned int w0 = (unsigned int)__shfl((int)pw, fl);
                if (lane == 0) s_t = fl * 32 + __builtin_ctz(w0);
            }
            if (tid == 0) { s_death += (double)ev[r]; cstate[c] = 2; }
            __syncthreads();
            const int t = s_t, tw = t >> 5;
            const unsigned int tb = 1u << (t & 31);
            const unsigned int pw = u.pbuf[c][lane];
            for (int rr0 = wid * 64; rr0 < NEDGE; rr0 += 1024) {
                const int rr = rr0 + lane;
                unsigned int hit = (rr < NEDGE) ? (Row[rr][tw] & tb) : 0u;
                unsigned long long mrows = __ballot(hit != 0u);
                while (mrows) {
                    const int rx = rr0 + __builtin_ctzll(mrows);
                    mrows &= mrows - 1;
                    Row[rx][lane] ^= pw;
                }
            }
            __threadfence_block();
            __syncthreads();
            {
                const unsigned int rrow2 = Row[r][lane];
                for (int idx = wid; idx < cnt; idx += 16) {
                    if (cstate[idx] != 1) continue;
                    unsigned long long mm = mask;
                    for (int s = 0; s < idx; ++s) mm &= mm - 1;
                    const int k = __builtin_ctzll(mm);
                    const int a = __shfl(a_l, k);
                    const int b = __shfl(b_l, k);
                    const unsigned int p2 = Row[a][lane] ^ Row[b][lane] ^ rrow2;
                    u.pbuf[idx][lane] = p2;
                    const bool indep = (__ballot(p2 != 0u) != 0ull);
                    if (lane == 0) cstate[idx] = indep ? 1 : 0;
                }
            }
            __syncthreads();
        }
        __syncthreads();
    }

    if (tid == 0) g_tp[cls] = (float)(s_death - s_birth);
}

__global__ void final_k(const float* __restrict__ tgt, float* __restrict__ out) {
    double total = 0.0;
    int valid = 0;
    for (int c = 0; c < NCLS; ++c) {
        if (g_counts[c] >= MIN_SAMP) {
            double tpt = 0.0;
            for (int p = 0; p < 100; ++p)
                tpt += (double)tgt[(c * 100 + p) * 2 + 1] - (double)tgt[(c * 100 + p) * 2 + 0];
            double d = (double)g_tp[c] - tpt;
            total += d * d;
            valid++;
        }
    }
    *out = valid ? (float)(total / valid) : 0.0f;
}

extern "C" void kernel_launch(void* const* d_in, const int* in_sizes, int n_in,
                              void* d_out, int out_size, void* d_ws, size_t ws_size,
                              hipStream_t stream) {
    const float* feat   = (const float*)d_in[0];
    const int*   labels = (const int*)d_in[1];
    const float* tgt    = (const float*)d_in[2];
    const int N = in_sizes[1];

    hipLaunchKernelGGL(init_k,         dim3(1),    dim3(64),   0, stream);
    hipLaunchKernelGGL(count_k,        dim3(256),  dim3(256),  0, stream, labels, N);
    hipLaunchKernelGGL(select_k,       dim3(1),    dim3(64),   0, stream, labels, N);
    hipLaunchKernelGGL(dist_k,         dim3(NCLS), dim3(1024), 0, stream, feat);
    hipLaunchKernelGGL(persist_fast_k, dim3(NCLS), dim3(1024), 0, stream);
    hipLaunchKernelGGL(persist_exact_k,dim3(NCLS), dim3(1024), 0, stream);
    hipLaunchKernelGGL(final_k,        dim3(1),    dim3(1),    0, stream, tgt, (float*)d_out);
}